// Round 12
// baseline (456.880 us; speedup 1.0000x reference)
//
#include <hip/hip_runtime.h>
#include <math.h>

#define BB 32
#define LL 512
#define DD 32
#define KK 6
#define OO 192
#define DM 512
#define MAGIC 0x1357A5A5

typedef __fp16 h2 __attribute__((ext_vector_type(2)));
union F2H { float f; h2 h; };
__device__ __forceinline__ float asF(h2 h) { F2H u; u.h = h; return u.f; }
__device__ __forceinline__ h2 asH(float f) { F2H u; u.f = f; return u.h; }

typedef short bf16x8 __attribute__((ext_vector_type(8)));
typedef float f4 __attribute__((ext_vector_type(4)));
union U16x8 { uint4 u; bf16x8 h; };

__device__ __forceinline__ unsigned short f2bf(float x) {   // RNE f32->bf16
  unsigned int u = __float_as_uint(x);
  u = (u + 0x7FFF + ((u >> 16) & 1)) >> 16;
  return (unsigned short)u;
}

#define MOVDPP(x, ctrl) \
  __int_as_float(__builtin_amdgcn_mov_dpp(__float_as_int(x), ctrl, 0xf, 0xf, true))

// LDS layout (floats), phase-overlaid. 5248 floats = 21 KB.
#define TLO   0
#define TXO   3152
#define CSTR  520
#define XCOL  0
#define XV    3120
#define YDMB  3648
#define MEDO  5184
#define STDO  5191
#define SAO   5198
#define SCO   5204
#define VSH   0
#define YSH   2112
#define GTE   4224
#define SCL   4256
#define OFS   4288
#define LDSF  5248

// ---- flag sync: deadlock-free at any occupancy (waiters never block producers)
__device__ __forceinline__ void set_flag(int* flags, int idx, int tid) {
  __threadfence();            // every thread releases its own writes to agent scope
  __syncthreads();
  if (tid == 0)
    __hip_atomic_store(&flags[idx], MAGIC, __ATOMIC_RELEASE, __HIP_MEMORY_SCOPE_AGENT);
}
__device__ __forceinline__ void wait_flags(int* flags, int lo, int n, int tid) {
  for (int i = tid; i < n; i += 256) {
    while (__hip_atomic_load(&flags[lo + i], __ATOMIC_RELAXED,
                             __HIP_MEMORY_SCOPE_AGENT) != MAGIC)
      __builtin_amdgcn_s_sleep(2);
  }
  __threadfence();            // acquire: invalidate stale cache before data reads
  __syncthreads();
}

// ---------------------------------------------------------------------------
// In-register bitonic sort of 512 floats across one wave (8 elems/lane).
// ---------------------------------------------------------------------------
__device__ __forceinline__ void sort512(float v[8], int lane) {
  #pragma unroll
  for (int k = 2; k <= 512; k <<= 1) {
    #pragma unroll
    for (int j = k >> 1; j > 0; j >>= 1) {
      if (j >= 8) {
        int jj = j >> 3;
        bool lower = (lane & jj) == 0;
        bool asc = ((lane << 3) & k) == 0;
        bool keepmin = (asc == lower);
        #pragma unroll
        for (int r = 0; r < 8; ++r) {
          float o;
          if (jj == 1)      o = MOVDPP(v[r], 0xB1);   // quad_perm [1,0,3,2]
          else if (jj == 2) o = MOVDPP(v[r], 0x4E);   // quad_perm [2,3,0,1]
          else if (jj == 8) o = MOVDPP(v[r], 0x128);  // row_ror:8 == xor8
          else              o = __shfl_xor(v[r], jj);
          v[r] = keepmin ? fminf(v[r], o) : fmaxf(v[r], o);
        }
      } else {
        #pragma unroll
        for (int r = 0; r < 8; ++r) {
          if ((r & j) == 0) {
            int r2 = r | j;
            bool asc = (((lane << 3) | r) & k) == 0;
            float a = v[r], b = v[r2];
            float lo = fminf(a, b), hi = fmaxf(a, b);
            v[r]  = asc ? lo : hi;
            v[r2] = asc ? hi : lo;
          }
        }
      }
    }
  }
}

// ---------------------------------------------------------------------------
// Mega-kernel, plain launch, 1024 blocks x 256 threads.
// P1 transpose -> flagA | P2 fused -> flagB | P3 mlp+bn -> flagC | P4 final
// ---------------------------------------------------------------------------
__global__ __launch_bounds__(256) void mega_kernel(
    const float* __restrict__ x, const float* __restrict__ x_date,
    const float* __restrict__ y_date, const float* __restrict__ w1,
    const float* __restrict__ b1, const float* __restrict__ w2,
    const float* __restrict__ b2, const float* __restrict__ gamma,
    const float* __restrict__ beta, float* __restrict__ out,
    float* __restrict__ V, float* __restrict__ ymean,
    unsigned short* __restrict__ errb, float* __restrict__ w0,
    float* __restrict__ accum, float* __restrict__ xt,
    float* __restrict__ xt2, unsigned short* __restrict__ w1t,
    int* __restrict__ flagA, int* __restrict__ flagB, int* __restrict__ flagC) {
  __shared__ float lds[LDSF];
  int g = blockIdx.x, tid = threadIdx.x;
  int lane = tid & 63, wv = tid >> 6;
  int b = g >> 5, d = g & 31;

  // ======================= P1: transposes =======================
  {
    int l0 = (g & 31) * 16;
    const float* src = x_date + (size_t)(b * LL + l0) * 192;
    #pragma unroll
    for (int it = 0; it < 3; ++it) {           // 16 rows x 48 float4
      int f = tid + it * 256;
      int row = f / 48, c4 = f % 48;
      float4 v = ((const float4*)(src + (size_t)row * 192))[c4];
      float* p = &lds[TLO + row * 197 + c4 * 4];
      p[0] = v.x; p[1] = v.y; p[2] = v.z; p[3] = v.w;
    }
    if (tid < 128) {                           // x tile: 16 rows x 32 (contig)
      int row = tid >> 3, c4 = tid & 7;
      float4 v = ((const float4*)(x + (size_t)(b * LL + l0) * DD))[tid];
      float* p = &lds[TXO + row * 37 + c4 * 4];
      p[0] = v.x; p[1] = v.y; p[2] = v.z; p[3] = v.w;
    }
    __syncthreads();
    #pragma unroll
    for (int it = 0; it < 3; ++it) {           // xt: 192 dk x 4 float4
      int f = tid + it * 256;
      int dk = f >> 2, c4 = f & 3;
      float4 v;
      v.x = lds[TLO + (c4 * 4 + 0) * 197 + dk];
      v.y = lds[TLO + (c4 * 4 + 1) * 197 + dk];
      v.z = lds[TLO + (c4 * 4 + 2) * 197 + dk];
      v.w = lds[TLO + (c4 * 4 + 3) * 197 + dk];
      ((float4*)(xt + (size_t)(b * 192 + dk) * LL + l0))[c4] = v;
    }
    if (tid < 128) {                           // xt2: 32 d x 4 float4
      int dd = tid >> 2, c4 = tid & 3;
      float4 v;
      v.x = lds[TXO + (c4 * 4 + 0) * 37 + dd];
      v.y = lds[TXO + (c4 * 4 + 1) * 37 + dd];
      v.z = lds[TXO + (c4 * 4 + 2) * 37 + dd];
      v.w = lds[TXO + (c4 * 4 + 3) * 37 + dd];
      ((float4*)(xt2 + (size_t)(b * DD + dd) * LL + l0))[c4] = v;
    }

    if (g < 64) {                              // w1 -> w1t bf16 (64x64 tile)
      __syncthreads();
      int l0w = (g & 7) * 64, m0 = (g >> 3) * 64;
      #pragma unroll
      for (int it = 0; it < 4; ++it) {
        int f = tid + it * 256;
        int row = f >> 4, c4 = f & 15;
        float4 v = ((const float4*)(w1 + (size_t)(l0w + row) * DM + m0))[c4];
        float* p = &lds[row * 68 + c4 * 4];
        p[0] = v.x; p[1] = v.y; p[2] = v.z; p[3] = v.w;
      }
      __syncthreads();
      unsigned int* w1t32 = (unsigned int*)w1t;
      #pragma unroll
      for (int it = 0; it < 8; ++it) {
        int f = tid + it * 256;
        int mr = f >> 5, c = f & 31;
        float a = lds[(c * 2 + 0) * 68 + mr];
        float bv = lds[(c * 2 + 1) * 68 + mr];
        unsigned int u = (unsigned int)f2bf(a) | ((unsigned int)f2bf(bv) << 16);
        w1t32[(size_t)(m0 + mr) * (DM / 2) + (l0w >> 1) + c] = u;
      }
    }
  }
  set_flag(flagA, g, tid);
  wait_flags(flagA, b * 32, 32, tid);    // my b-group's transposes done

  // ======================= P2: stats + attention =======================
  {
    const float* xtb = xt + (size_t)(b * 192 + d * 6) * LL;
    #pragma unroll
    for (int it = 0; it < 3; ++it) {
      int f = tid + it * 256;                  // 6 cols x 128 float4
      int c = f >> 7, c4 = f & 127;
      float4 v = ((const float4*)(xtb + (size_t)c * LL))[c4];
      *(float4*)&lds[XCOL + c * CSTR + c4 * 4] = v;
    }
    if (tid < 128) {
      float4 v = ((const float4*)(xt2 + (size_t)(b * DD + d) * LL))[tid];
      *(float4*)&lds[XV + tid * 4] = v;
    }
    __syncthreads();

    #pragma unroll
    for (int pass = 0; pass < 2; ++pass) {
      int s = pass * 4 + wv;
      if (s < 7) {
        float v[8];
        const float4* colp = (s < 6) ? (const float4*)&lds[XCOL + s * CSTR + lane * 8]
                                     : (const float4*)&lds[XV + lane * 8];
        float4 c0 = colp[0], c1 = colp[1];
        v[0]=c0.x; v[1]=c0.y; v[2]=c0.z; v[3]=c0.w;
        v[4]=c1.x; v[5]=c1.y; v[6]=c1.z; v[7]=c1.w;
        sort512(v, lane);
        float e127 = __shfl(v[7], 15);
        float e128 = __shfl(v[0], 16);
        float e255 = __shfl(v[7], 31);
        float e383 = __shfl(v[7], 47);
        float e384 = __shfl(v[0], 48);
        if (lane == 0) {
          float q25 = e127 + 0.75f * (e128 - e127);   // 0.25*(n-1)=127.75
          float q75 = e383 + 0.25f * (e384 - e383);   // 0.75*(n-1)=383.25
          lds[MEDO + s] = e255;                       // torch lower-median
          lds[STDO + s] = q75 - q25 + 1e-6f;
        }
      }
    }
    __syncthreads();

    if (tid < 6) {
      float a = lds[STDO + 6] / lds[STDO + tid];
      lds[SAO + tid] = a;
      lds[SCO + tid] = lds[MEDO + 6] - lds[MEDO + tid] * a;
    }
    __syncthreads();

    float ask[6], csk[6];
    #pragma unroll
    for (int k = 0; k < 6; ++k) { ask[k] = lds[SAO + k]; csk[k] = lds[SCO + k]; }

    const float PSC = 0.58912435f;   // (1/sqrt(6)) * log2(e)

    float4 packed[2];
    #pragma unroll
    for (int it = 0; it < 2; ++it) {
      int l = tid + it * 256;
      float m0 = ask[0]*lds[XCOL+0*CSTR+l] + csk[0];
      float m1 = ask[1]*lds[XCOL+1*CSTR+l] + csk[1];
      float m2 = ask[2]*lds[XCOL+2*CSTR+l] + csk[2];
      float m3 = ask[3]*lds[XCOL+3*CSTR+l] + csk[3];
      float m4 = ask[4]*lds[XCOL+4*CSTR+l] + csk[4];
      float m5 = ask[5]*lds[XCOL+5*CSTR+l] + csk[5];
      float xvv = lds[XV + l];
      errb[(size_t)g * LL + l] = f2bf(xvv - (m0+m1+m2+m3+m4+m5) * (1.0f/6.0f));
      packed[it].x = asF(__builtin_amdgcn_cvt_pkrtz(m0*PSC, m1*PSC));
      packed[it].y = asF(__builtin_amdgcn_cvt_pkrtz(m2*PSC, m3*PSC));
      packed[it].z = asF(__builtin_amdgcn_cvt_pkrtz(m4*PSC, m5*PSC));
      packed[it].w = asF(__builtin_amdgcn_cvt_pkrtz(xvv, 0.0f));
    }

    float4 ypk; float ymv; bool doY = (tid < OO);
    if (doY) {
      const float2* yp = (const float2*)(y_date + (((size_t)b * OO + tid) * DD + d) * KK);
      float2 y0 = yp[0], y1 = yp[1], y2 = yp[2];
      float q0 = ask[0]*y0.x + csk[0];
      float q1 = ask[1]*y0.y + csk[1];
      float q2 = ask[2]*y1.x + csk[2];
      float q3 = ask[3]*y1.y + csk[3];
      float q4 = ask[4]*y2.x + csk[4];
      float q5 = ask[5]*y2.y + csk[5];
      ymv = (q0+q1+q2+q3+q4+q5) * (1.0f/6.0f);
      ypk.x = asF(__builtin_amdgcn_cvt_pkrtz(q0, q1));
      ypk.y = asF(__builtin_amdgcn_cvt_pkrtz(q2, q3));
      ypk.z = asF(__builtin_amdgcn_cvt_pkrtz(q4, q5));
    }
    __syncthreads();   // XCOL reads done; overlay

    *(float4*)&lds[tid * 4]         = packed[0];
    *(float4*)&lds[(tid + 256) * 4] = packed[1];
    if (doY) {
      ymean[(size_t)g * OO + tid] = ymv;
      lds[YDMB + tid*4 + 0] = ypk.x;
      lds[YDMB + tid*4 + 1] = ypk.y;
      lds[YDMB + tid*4 + 2] = ypk.z;
    }
    __syncthreads();

    h2 yk[3][3];
    #pragma unroll
    for (int j = 0; j < 3; ++j) {
      int o = lane + 64 * j;
      yk[j][0] = asH(lds[YDMB + o*4 + 0]);
      yk[j][1] = asH(lds[YDMB + o*4 + 1]);
      yk[j][2] = asH(lds[YDMB + o*4 + 2]);
    }
    __syncthreads();

    float den[3] = {0.f,0.f,0.f}, num[3] = {0.f,0.f,0.f};
    int l0a = wv * 128;
    #pragma unroll 2
    for (int l = l0a; l < l0a + 128; ++l) {
      float4 rw = *(const float4*)&lds[l * 4];
      h2 x01 = asH(rw.x), x23 = asH(rw.y), x45 = asH(rw.z);
      float xf = (float)(asH(rw.w).x);
      #pragma unroll
      for (int j = 0; j < 3; ++j) {
        float sc = __builtin_amdgcn_fdot2(x01, yk[j][0], 0.0f, false);
        sc = __builtin_amdgcn_fdot2(x23, yk[j][1], sc, false);
        sc = __builtin_amdgcn_fdot2(x45, yk[j][2], sc, false);
        float e = exp2f(sc);
        den[j] += e;
        num[j] += e * xf;
      }
    }
    #pragma unroll
    for (int j = 0; j < 3; ++j) {
      lds[YDMB + wv*192 + lane + 64*j]       = den[j];
      lds[YDMB + 768 + wv*192 + lane + 64*j] = num[j];
    }
    __syncthreads();

    if (tid < OO) {
      float dsum = lds[YDMB + tid] + lds[YDMB + 192 + tid]
                 + lds[YDMB + 384 + tid] + lds[YDMB + 576 + tid];
      float nsum = lds[YDMB + 768 + tid] + lds[YDMB + 960 + tid]
                 + lds[YDMB + 1152 + tid] + lds[YDMB + 1344 + tid];
      V[(size_t)g * OO + tid] = nsum / dsum;
    }
  }
  set_flag(flagB, g, tid);
  if (g >= 128) return;                        // producers exit, free slots

  // ======================= P3: blocks 0..63 mlp | 96..127 bn ===============
  wait_flags(flagB, 0, 1024, tid);             // all V, errb, w1t complete

  if (g < 64) {
    int r0 = g * 16;
    int m16 = lane & 15, quad = lane >> 4;
    int mw = wv * 128;

    float b1v[8], w2d[8];
    #pragma unroll
    for (int ct = 0; ct < 8; ++ct) {
      int m = mw + ct * 16 + m16;
      b1v[ct] = b1[m];
      float2 w2p = ((const float2*)w2)[m];
      w2d[ct] = w2p.x - w2p.y;
    }

    f4 acc[8];
    #pragma unroll
    for (int ct = 0; ct < 8; ++ct) acc[ct] = (f4){0.f, 0.f, 0.f, 0.f};

    const unsigned short* ea = errb + (size_t)(r0 + m16) * DM + quad * 8;
    const unsigned short* wb = w1t + (size_t)(mw + m16) * DM + quad * 8;

    for (int ks = 0; ks < DM; ks += 32) {
      U16x8 ua;
      ua.u = *(const uint4*)(ea + ks);
      #pragma unroll
      for (int ct = 0; ct < 8; ++ct) {
        U16x8 ub;
        ub.u = *(const uint4*)(wb + (size_t)ct * 16 * DM + ks);
        acc[ct] = __builtin_amdgcn_mfma_f32_16x16x32_bf16(ua.h, ub.h, acc[ct], 0, 0, 0);
      }
    }

    float rsum[4] = {0.f, 0.f, 0.f, 0.f};
    #pragma unroll
    for (int ct = 0; ct < 8; ++ct) {
      #pragma unroll
      for (int r = 0; r < 4; ++r) {
        float h = acc[ct][r] + b1v[ct];
        float gg = 0.5f * h * (1.0f + erff(h * 0.70710678f));
        rsum[r] += gg * w2d[ct];
      }
    }
    #pragma unroll
    for (int r = 0; r < 4; ++r) {
      rsum[r] += __shfl_xor(rsum[r], 1);
      rsum[r] += __shfl_xor(rsum[r], 2);
      rsum[r] += __shfl_xor(rsum[r], 4);
      rsum[r] += __shfl_xor(rsum[r], 8);
    }
    if (m16 == 0) {
      #pragma unroll
      for (int r = 0; r < 4; ++r)
        lds[wv * 16 + quad * 4 + r] = rsum[r];
    }
    __syncthreads();
    if (tid < 16) {
      float ld = b2[0] - b2[1]
               + lds[tid] + lds[16 + tid] + lds[32 + tid] + lds[48 + tid];
      w0[r0 + tid] = 1.0f / (1.0f + expf(-ld));
    }
    set_flag(flagC, g, tid);
  } else if (g >= 96) {
    // ---- bn stats for d = g - 96 over (B, O) of V ----
    int dd = g - 96;
    float s = 0.0f, s2 = 0.0f;
    for (int i = tid; i < BB * OO; i += 256) {
      int bb = i / OO, o = i - bb * OO;
      float v = V[((size_t)bb * DD + dd) * OO + o];
      s += v; s2 += v * v;
    }
    #pragma unroll
    for (int off = 32; off > 0; off >>= 1) {
      s  += __shfl_down(s, off);
      s2 += __shfl_down(s2, off);
    }
    __syncthreads();
    if (lane == 0) { lds[wv] = s; lds[4 + wv] = s2; }
    __syncthreads();
    if (tid == 0) {
      float S  = lds[0] + lds[1] + lds[2] + lds[3];
      float S2 = lds[4] + lds[5] + lds[6] + lds[7];
      const float inv = 1.0f / (BB * OO);
      float mu = S * inv;
      accum[dd] = mu;
      accum[DD + dd] = S2 * inv - mu * mu;   // var
    }
    set_flag(flagC, g, tid);
    return;
  } else {
    set_flag(flagC, g, tid);                  // blocks 64..95: no P3 work
  }

  // ======================= P4: final fusion, blocks 0..95 ==================
  wait_flags(flagC, 0, 64, tid);
  wait_flags(flagC, 96, 32, tid);

  {
    int bb = g / 3, o0 = (g - bb * 3) * 64;

    #pragma unroll
    for (int it = 0; it < 2; ++it) {           // 32 d x 16 float4 (64 o)
      int f = tid + it * 256;
      int dd = f >> 4, c4 = f & 15;
      size_t goff = (size_t)(bb * DD + dd) * OO + o0;
      float4 v = ((const float4*)(V + goff))[c4];
      float4 y = ((const float4*)(ymean + goff))[c4];
      float* pv = &lds[VSH + dd * 66 + c4 * 4];
      float* py = &lds[YSH + dd * 66 + c4 * 4];
      pv[0]=v.x; pv[1]=v.y; pv[2]=v.z; pv[3]=v.w;
      py[0]=y.x; py[1]=y.y; py[2]=y.z; py[3]=y.w;
    }
    if (tid < 32) {
      float mu = accum[tid];
      float var = accum[DD + tid];
      float gg = gamma[tid] * rsqrtf(var + 1e-5f);
      lds[GTE + tid] = w0[bb * DD + tid];
      lds[SCL + tid] = gg;
      lds[OFS + tid] = beta[tid] - mu * gg;
    }
    __syncthreads();

    #pragma unroll
    for (int it = 0; it < 2; ++it) {           // 64 o x 8 float4 (32 d)
      int f = tid + it * 256;
      int op = f >> 3, c4 = f & 7;
      float4 r;
      #pragma unroll
      for (int j = 0; j < 4; ++j) {
        int dd = c4 * 4 + j;
        float v  = lds[VSH + dd * 66 + op];
        float ym = lds[YSH + dd * 66 + op];
        float gg = lds[GTE + dd];
        float y  = v * lds[SCL + dd] + lds[OFS + dd];
        ((float*)&r)[j] = ym * gg + y * (1.0f - gg);
      }
      ((float4*)(out + (size_t)(bb * OO + o0 + op) * DD))[c4] = r;
    }
  }
}

// ---------------------------------------------------------------------------
extern "C" void kernel_launch(void* const* d_in, const int* in_sizes, int n_in,
                              void* d_out, int out_size, void* d_ws, size_t ws_size,
                              hipStream_t stream) {
  const float* x      = (const float*)d_in[0];
  const float* x_date = (const float*)d_in[1];
  const float* y_date = (const float*)d_in[2];
  const float* w1     = (const float*)d_in[3];
  const float* b1     = (const float*)d_in[4];
  const float* w2     = (const float*)d_in[5];
  const float* b2     = (const float*)d_in[6];
  const float* gamma  = (const float*)d_in[7];
  const float* beta   = (const float*)d_in[8];
  float* out = (float*)d_out;

  float* ws    = (float*)d_ws;
  float* V     = ws;                             // 196608  (B,D,O)
  float* ymean = ws + 196608;                    // 196608  (B,D,O)
  unsigned short* errb = (unsigned short*)(ws + 393216);   // 1024x512 bf16
  float* w0    = ws + 655360;                    // 1024
  float* accum = ws + 656384;                    // 64 (mu, var per d)
  float* xt    = ws + 656448;                    // 3145728 (B,192,L)
  float* xt2   = ws + 3802176;                   // 524288  (B,D,L)
  unsigned short* w1t = (unsigned short*)(ws + 4326464);   // 512x512 bf16
  int* flagA   = (int*)(ws + 4457536);           // 1024 (poisoned != MAGIC)
  int* flagB   = (int*)(ws + 4458560);           // 1024
  int* flagC   = (int*)(ws + 4459584);           // 128

  mega_kernel<<<1024, 256, 0, stream>>>(
      x, x_date, y_date, w1, b1, w2, b2, gamma, beta, out,
      V, ymean, errb, w0, accum, xt, xt2, w1t, flagA, flagB, flagC);
}

// Round 13
// 162.130 us; speedup vs baseline: 2.8180x; 2.8180x over previous
//
#include <hip/hip_runtime.h>
#include <math.h>

#define BB 32
#define LL 512
#define DD 32
#define KK 6
#define OO 192
#define DM 512

typedef __fp16 h2 __attribute__((ext_vector_type(2)));
union F2H { float f; h2 h; };
__device__ __forceinline__ float asF(h2 h) { F2H u; u.h = h; return u.f; }
__device__ __forceinline__ h2 asH(float f) { F2H u; u.f = f; return u.h; }

typedef short bf16x8 __attribute__((ext_vector_type(8)));
typedef float f4 __attribute__((ext_vector_type(4)));
union U16x8 { uint4 u; bf16x8 h; };

__device__ __forceinline__ unsigned short f2bf(float x) {   // RNE f32->bf16
  unsigned int u = __float_as_uint(x);
  u = (u + 0x7FFF + ((u >> 16) & 1)) >> 16;
  return (unsigned short)u;
}

#define MOVDPP(x, ctrl) \
  __int_as_float(__builtin_amdgcn_mov_dpp(__float_as_int(x), ctrl, 0xf, 0xf, true))

// LDS layout (float slots) for fused kernel
#define CSTR  520
#define XCOL  0                 // 7 cols x 520 f32; cols 0-5 overlaid by f16 rows later
#define XV    3120              // = XCOL + 6*CSTR : x column stays f32
#define YDMB  3648              // 192 x 4 (packed y f16); overlaid by DEN/NUM 2x768
#define BNP   5184              // 8 floats bn partials (overlays dead MEDO/STDO)
#define MEDO  5184
#define STDO  5191
#define SAO   5198
#define SCO   5204
#define LDSF  5216              // 20.9 KB

// ---------------------------------------------------------------------------
// K1 prep:
//  bids 0..255  : (b, l-chunk of 64): x_date -> xt (b,dk,l) AND x -> xt2 (b,d,l)
//  bids 256..319: w1 (l,m) f32 -> w1t (m,l) bf16 (64x64 tiles)
//  bid 0 also zeroes accum (read by K2's atomics after the kernel boundary).
// ---------------------------------------------------------------------------
__global__ __launch_bounds__(256) void prep_kernel(
    const float* __restrict__ x, const float* __restrict__ x_date,
    float* __restrict__ xt, float* __restrict__ xt2,
    const float* __restrict__ w1, unsigned short* __restrict__ w1t,
    float* __restrict__ accum) {
  int bid = blockIdx.x, tid = threadIdx.x;

  if (bid == 0 && tid < 64) accum[tid] = 0.0f;

  if (bid < 256) {
    __shared__ float tl[64 * 197];   // stride 197 kills transpose bank conflicts
    __shared__ float tx[64 * 37];
    int b = bid >> 3, l0 = (bid & 7) * 64;

    const float* src = x_date + (size_t)(b * LL + l0) * 192;
    #pragma unroll
    for (int it = 0; it < 12; ++it) {           // 64 rows x 48 float4 reads
      int f = tid + it * 256;
      int row = f / 48, c4 = f % 48;
      float4 v = ((const float4*)(src + (size_t)row * 192))[c4];
      float* p = &tl[row * 197 + c4 * 4];
      p[0] = v.x; p[1] = v.y; p[2] = v.z; p[3] = v.w;
    }
    const float* srcx = x + (size_t)(b * LL + l0) * DD;
    #pragma unroll
    for (int it = 0; it < 2; ++it) {            // 64 rows x 8 float4
      int f = tid + it * 256;
      int row = f >> 3, c4 = f & 7;
      float4 v = ((const float4*)srcx)[f];
      float* p = &tx[row * 37 + c4 * 4];
      p[0] = v.x; p[1] = v.y; p[2] = v.z; p[3] = v.w;
    }
    __syncthreads();

    #pragma unroll
    for (int it = 0; it < 12; ++it) {           // 192 dk-rows x 16 float4
      int f = tid + it * 256;
      int dk = f >> 4, c4 = f & 15;
      float4 v;
      v.x = tl[(c4 * 4 + 0) * 197 + dk];
      v.y = tl[(c4 * 4 + 1) * 197 + dk];
      v.z = tl[(c4 * 4 + 2) * 197 + dk];
      v.w = tl[(c4 * 4 + 3) * 197 + dk];
      ((float4*)(xt + (size_t)(b * 192 + dk) * LL + l0))[c4] = v;
    }
    #pragma unroll
    for (int it = 0; it < 2; ++it) {            // 32 d-rows x 16 float4
      int f = tid + it * 256;
      int d = f >> 4, c4 = f & 15;
      float4 v;
      v.x = tx[(c4 * 4 + 0) * 37 + d];
      v.y = tx[(c4 * 4 + 1) * 37 + d];
      v.z = tx[(c4 * 4 + 2) * 37 + d];
      v.w = tx[(c4 * 4 + 3) * 37 + d];
      ((float4*)(xt2 + (size_t)(b * DD + d) * LL + l0))[c4] = v;
    }
  } else {
    // ---- w1 -> w1t bf16, 64x64 tile ----
    __shared__ float tw[64 * 68];
    int id = bid - 256;                         // 0..63
    int l0 = (id & 7) * 64, m0 = (id >> 3) * 64;
    #pragma unroll
    for (int it = 0; it < 4; ++it) {            // 64 l-rows x 16 float4
      int f = tid + it * 256;
      int row = f >> 4, c4 = f & 15;
      float4 v = ((const float4*)(w1 + (size_t)(l0 + row) * DM + m0))[c4];
      float* p = &tw[row * 68 + c4 * 4];
      p[0] = v.x; p[1] = v.y; p[2] = v.z; p[3] = v.w;
    }
    __syncthreads();
    unsigned int* w1t32 = (unsigned int*)w1t;
    #pragma unroll
    for (int it = 0; it < 8; ++it) {            // 64 m-rows x 32 uints
      int f = tid + it * 256;
      int mr = f >> 5, c = f & 31;
      float a = tw[(c * 2 + 0) * 68 + mr];
      float b = tw[(c * 2 + 1) * 68 + mr];
      unsigned int u = (unsigned int)f2bf(a) | ((unsigned int)f2bf(b) << 16);
      w1t32[(size_t)(m0 + mr) * (DM / 2) + (l0 >> 1) + c] = u;
    }
  }
}

// ---------------------------------------------------------------------------
// In-register bitonic sort of 512 floats across one wave (8 elems/lane).
// Lane-xor 1/2/8 via DPP (VALU pipe); 4/16/32 via shfl (LDS pipe).
// ---------------------------------------------------------------------------
__device__ __forceinline__ void sort512(float v[8], int lane) {
  #pragma unroll
  for (int k = 2; k <= 512; k <<= 1) {
    #pragma unroll
    for (int j = k >> 1; j > 0; j >>= 1) {
      if (j >= 8) {
        int jj = j >> 3;
        bool lower = (lane & jj) == 0;
        bool asc = ((lane << 3) & k) == 0;
        bool keepmin = (asc == lower);
        #pragma unroll
        for (int r = 0; r < 8; ++r) {
          float o;
          if (jj == 1)      o = MOVDPP(v[r], 0xB1);   // quad_perm [1,0,3,2]
          else if (jj == 2) o = MOVDPP(v[r], 0x4E);   // quad_perm [2,3,0,1]
          else if (jj == 8) o = MOVDPP(v[r], 0x128);  // row_ror:8 == xor8
          else              o = __shfl_xor(v[r], jj);
          v[r] = keepmin ? fminf(v[r], o) : fmaxf(v[r], o);
        }
      } else {
        #pragma unroll
        for (int r = 0; r < 8; ++r) {
          if ((r & j) == 0) {
            int r2 = r | j;
            bool asc = (((lane << 3) | r) & k) == 0;
            float a = v[r], b = v[r2];
            float lo = fminf(a, b), hi = fmaxf(a, b);
            v[r]  = asc ? lo : hi;
            v[r2] = asc ? hi : lo;
          }
        }
      }
    }
  }
}

// ---------------------------------------------------------------------------
// K2 fused: per-(b,d) order stats + affine map + attention + err(bf16) +
// ymean + bn partial sums (atomicAdd). Verbatim R10 (58 us).
// ---------------------------------------------------------------------------
__global__ __launch_bounds__(256) void fused_kernel(
    const float* __restrict__ xt, const float* __restrict__ xt2,
    const float* __restrict__ y_date,
    float* __restrict__ V, float* __restrict__ ymean,
    unsigned short* __restrict__ errb, float* __restrict__ accum) {
  __shared__ float lds[LDSF];
  int bid = blockIdx.x, b = bid >> 5, d = bid & 31;
  int tid = threadIdx.x, lane = tid & 63, wv = tid >> 6;

  const float* xtb = xt + (size_t)(b * 192 + d * 6) * LL;
  #pragma unroll
  for (int it = 0; it < 3; ++it) {
    int f = tid + it * 256;                    // 6 cols x 128 float4
    int c = f >> 7, c4 = f & 127;
    float4 v = ((const float4*)(xtb + (size_t)c * LL))[c4];
    *(float4*)&lds[XCOL + c * CSTR + c4 * 4] = v;
  }
  if (tid < 128) {
    float4 v = ((const float4*)(xt2 + (size_t)(b * DD + d) * LL))[tid];
    *(float4*)&lds[XV + tid * 4] = v;
  }
  __syncthreads();

  #pragma unroll
  for (int pass = 0; pass < 2; ++pass) {
    int s = pass * 4 + wv;
    if (s < 7) {
      float v[8];
      const float4* colp = (s < 6) ? (const float4*)&lds[XCOL + s * CSTR + lane * 8]
                                   : (const float4*)&lds[XV + lane * 8];
      float4 c0 = colp[0], c1 = colp[1];
      v[0]=c0.x; v[1]=c0.y; v[2]=c0.z; v[3]=c0.w;
      v[4]=c1.x; v[5]=c1.y; v[6]=c1.z; v[7]=c1.w;
      sort512(v, lane);
      float e127 = __shfl(v[7], 15);
      float e128 = __shfl(v[0], 16);
      float e255 = __shfl(v[7], 31);
      float e383 = __shfl(v[7], 47);
      float e384 = __shfl(v[0], 48);
      if (lane == 0) {
        float q25 = e127 + 0.75f * (e128 - e127);   // 0.25*(n-1)=127.75
        float q75 = e383 + 0.25f * (e384 - e383);   // 0.75*(n-1)=383.25
        lds[MEDO + s] = e255;                       // torch lower-median
        lds[STDO + s] = q75 - q25 + 1e-6f;
      }
    }
  }
  __syncthreads();

  if (tid < 6) {
    float a = lds[STDO + 6] / lds[STDO + tid];
    lds[SAO + tid] = a;
    lds[SCO + tid] = lds[MEDO + 6] - lds[MEDO + tid] * a;
  }
  __syncthreads();

  float ask[6], csk[6];
  #pragma unroll
  for (int k = 0; k < 6; ++k) { ask[k] = lds[SAO + k]; csk[k] = lds[SCO + k]; }

  const float PSC = 0.58912435f;   // (1/sqrt(6)) * log2(e)

  float4 packed[2];
  #pragma unroll
  for (int it = 0; it < 2; ++it) {
    int l = tid + it * 256;
    float m0 = ask[0]*lds[XCOL+0*CSTR+l] + csk[0];
    float m1 = ask[1]*lds[XCOL+1*CSTR+l] + csk[1];
    float m2 = ask[2]*lds[XCOL+2*CSTR+l] + csk[2];
    float m3 = ask[3]*lds[XCOL+3*CSTR+l] + csk[3];
    float m4 = ask[4]*lds[XCOL+4*CSTR+l] + csk[4];
    float m5 = ask[5]*lds[XCOL+5*CSTR+l] + csk[5];
    float xvv = lds[XV + l];
    errb[(size_t)bid * LL + l] = f2bf(xvv - (m0+m1+m2+m3+m4+m5) * (1.0f/6.0f));
    packed[it].x = asF(__builtin_amdgcn_cvt_pkrtz(m0*PSC, m1*PSC));
    packed[it].y = asF(__builtin_amdgcn_cvt_pkrtz(m2*PSC, m3*PSC));
    packed[it].z = asF(__builtin_amdgcn_cvt_pkrtz(m4*PSC, m5*PSC));
    packed[it].w = asF(__builtin_amdgcn_cvt_pkrtz(xvv, 0.0f));
  }

  float4 ypk; float ymv; bool doY = (tid < OO);
  if (doY) {
    const float2* yp = (const float2*)(y_date + (((size_t)b * OO + tid) * DD + d) * KK);
    float2 y0 = yp[0], y1 = yp[1], y2 = yp[2];
    float q0 = ask[0]*y0.x + csk[0];
    float q1 = ask[1]*y0.y + csk[1];
    float q2 = ask[2]*y1.x + csk[2];
    float q3 = ask[3]*y1.y + csk[3];
    float q4 = ask[4]*y2.x + csk[4];
    float q5 = ask[5]*y2.y + csk[5];
    ymv = (q0+q1+q2+q3+q4+q5) * (1.0f/6.0f);
    ypk.x = asF(__builtin_amdgcn_cvt_pkrtz(q0, q1));
    ypk.y = asF(__builtin_amdgcn_cvt_pkrtz(q2, q3));
    ypk.z = asF(__builtin_amdgcn_cvt_pkrtz(q4, q5));
  }
  __syncthreads();   // all XCOL reads done; safe to overlay

  *(float4*)&lds[tid * 4]         = packed[0];
  *(float4*)&lds[(tid + 256) * 4] = packed[1];
  if (doY) {
    ymean[(size_t)bid * OO + tid] = ymv;
    lds[YDMB + tid*4 + 0] = ypk.x;
    lds[YDMB + tid*4 + 1] = ypk.y;
    lds[YDMB + tid*4 + 2] = ypk.z;
  }
  __syncthreads();

  h2 yk[3][3];
  #pragma unroll
  for (int j = 0; j < 3; ++j) {
    int o = lane + 64 * j;
    yk[j][0] = asH(lds[YDMB + o*4 + 0]);
    yk[j][1] = asH(lds[YDMB + o*4 + 1]);
    yk[j][2] = asH(lds[YDMB + o*4 + 2]);
  }
  __syncthreads();   // yk loaded; DEN/NUM overlay YDM

  float den[3] = {0.f,0.f,0.f}, num[3] = {0.f,0.f,0.f};
  int l0 = wv * 128;
  #pragma unroll 2
  for (int l = l0; l < l0 + 128; ++l) {
    float4 rw = *(const float4*)&lds[l * 4];
    h2 x01 = asH(rw.x), x23 = asH(rw.y), x45 = asH(rw.z);
    float xf = (float)(asH(rw.w).x);
    #pragma unroll
    for (int j = 0; j < 3; ++j) {
      float sc = __builtin_amdgcn_fdot2(x01, yk[j][0], 0.0f, false);
      sc = __builtin_amdgcn_fdot2(x23, yk[j][1], sc, false);
      sc = __builtin_amdgcn_fdot2(x45, yk[j][2], sc, false);
      float e = exp2f(sc);     // scale folded into x-side pack
      den[j] += e;
      num[j] += e * xf;
    }
  }
  #pragma unroll
  for (int j = 0; j < 3; ++j) {
    lds[YDMB + wv*192 + lane + 64*j]       = den[j];
    lds[YDMB + 768 + wv*192 + lane + 64*j] = num[j];
  }
  __syncthreads();

  float v = 0.0f;
  if (tid < OO) {
    float dsum = lds[YDMB + tid] + lds[YDMB + 192 + tid]
               + lds[YDMB + 384 + tid] + lds[YDMB + 576 + tid];
    float nsum = lds[YDMB + 768 + tid] + lds[YDMB + 960 + tid]
               + lds[YDMB + 1152 + tid] + lds[YDMB + 1344 + tid];
    v = nsum / dsum;
    V[(size_t)bid * OO + tid] = v;
  }

  __syncthreads();                 // YDMB reads done; BNP overlays safe
  float s1 = v, s2 = v * v;
  #pragma unroll
  for (int off = 32; off > 0; off >>= 1) {
    s1 += __shfl_down(s1, off);
    s2 += __shfl_down(s2, off);
  }
  if (lane == 0) { lds[BNP + wv] = s1; lds[BNP + 4 + wv] = s2; }
  __syncthreads();
  if (tid == 0) {
    float S  = lds[BNP+0] + lds[BNP+1] + lds[BNP+2] + lds[BNP+3];
    float S2 = lds[BNP+4] + lds[BNP+5] + lds[BNP+6] + lds[BNP+7];
    atomicAdd(&accum[d], S);
    atomicAdd(&accum[DD + d], S2);
  }
}

// ---------------------------------------------------------------------------
// K3 tail: 64 blocks = (b, o-half). Each block REDUNDANTLY computes its b's
// 32-row gating GEMM (no cross-block dependency -> no flags/fences), bn
// normalization constants from accum, then the final fusion for its half.
// ---------------------------------------------------------------------------
__global__ __launch_bounds__(256) void tail_kernel(
    const unsigned short* __restrict__ errb, const unsigned short* __restrict__ w1t,
    const float* __restrict__ b1, const float* __restrict__ w2,
    const float* __restrict__ b2, const float* __restrict__ V,
    const float* __restrict__ ymean, const float* __restrict__ accum,
    const float* __restrict__ gamma, const float* __restrict__ beta,
    float* __restrict__ out) {
  __shared__ float vsh[32 * 100], ysh[32 * 100];
  __shared__ float part[4][32];
  __shared__ float gsh[32], ssh[32], osh[32];
  int g = blockIdx.x, tid = threadIdx.x;
  int b = g >> 1, o0 = (g & 1) * 96;
  int lane = tid & 63, wv = tid >> 6;
  int m16 = lane & 15, quad = lane >> 4;
  int mw = wv * 128;
  int r0 = b * 32;

  // ---- stage V/ymean for (b, o-half): 32 d x 24 float4 ----
  #pragma unroll
  for (int it = 0; it < 3; ++it) {
    int f = tid + it * 256;
    int d = f / 24, c4 = f % 24;
    size_t goff = (size_t)(b * DD + d) * OO + o0;
    float4 v = ((const float4*)(V + goff))[c4];
    float4 y = ((const float4*)(ymean + goff))[c4];
    float* pv = &vsh[d * 100 + c4 * 4];
    float* py = &ysh[d * 100 + c4 * 4];
    pv[0]=v.x; pv[1]=v.y; pv[2]=v.z; pv[3]=v.w;
    py[0]=y.x; py[1]=y.y; py[2]=y.z; py[3]=y.w;
  }

  // ---- gating GEMM: rows r0..r0+31 x all 512 m (wave: 128 m) ----
  float b1v[8], w2d[8];
  #pragma unroll
  for (int ct = 0; ct < 8; ++ct) {
    int m = mw + ct * 16 + m16;
    b1v[ct] = b1[m];
    float2 w2p = ((const float2*)w2)[m];
    w2d[ct] = w2p.x - w2p.y;
  }

  f4 acc[2][8];
  #pragma unroll
  for (int rt = 0; rt < 2; ++rt)
    #pragma unroll
    for (int ct = 0; ct < 8; ++ct)
      acc[rt][ct] = (f4){0.f, 0.f, 0.f, 0.f};

  const unsigned short* ea = errb + (size_t)(r0 + m16) * DM + quad * 8;
  const unsigned short* eb = ea + 16 * DM;
  const unsigned short* wb = w1t + (size_t)(mw + m16) * DM + quad * 8;

  for (int ks = 0; ks < DM; ks += 32) {
    U16x8 ua0, ua1;
    ua0.u = *(const uint4*)(ea + ks);
    ua1.u = *(const uint4*)(eb + ks);
    #pragma unroll
    for (int ct = 0; ct < 8; ++ct) {
      U16x8 ub;
      ub.u = *(const uint4*)(wb + (size_t)ct * 16 * DM + ks);
      acc[0][ct] = __builtin_amdgcn_mfma_f32_16x16x32_bf16(ua0.h, ub.h, acc[0][ct], 0, 0, 0);
      acc[1][ct] = __builtin_amdgcn_mfma_f32_16x16x32_bf16(ua1.h, ub.h, acc[1][ct], 0, 0, 0);
    }
  }

  #pragma unroll
  for (int rt = 0; rt < 2; ++rt) {
    float rsum[4] = {0.f, 0.f, 0.f, 0.f};
    #pragma unroll
    for (int ct = 0; ct < 8; ++ct) {
      #pragma unroll
      for (int r = 0; r < 4; ++r) {
        float h = acc[rt][ct][r] + b1v[ct];
        float gg = 0.5f * h * (1.0f + erff(h * 0.70710678f));
        rsum[r] += gg * w2d[ct];
      }
    }
    #pragma unroll
    for (int r = 0; r < 4; ++r) {
      rsum[r] += __shfl_xor(rsum[r], 1);
      rsum[r] += __shfl_xor(rsum[r], 2);
      rsum[r] += __shfl_xor(rsum[r], 4);
      rsum[r] += __shfl_xor(rsum[r], 8);
    }
    if (m16 == 0) {
      #pragma unroll
      for (int r = 0; r < 4; ++r)
        part[wv][rt * 16 + quad * 4 + r] = rsum[r];
    }
  }
  __syncthreads();

  if (tid < 32) {
    float ld = b2[0] - b2[1]
             + part[0][tid] + part[1][tid] + part[2][tid] + part[3][tid];
    gsh[tid] = 1.0f / (1.0f + expf(-ld));      // gate w0 for (b, d=tid)
    const float inv = 1.0f / (BB * OO);
    float mu = accum[tid] * inv;
    float var = accum[DD + tid] * inv - mu * mu;
    float gg = gamma[tid] * rsqrtf(var + 1e-5f);
    ssh[tid] = gg;
    osh[tid] = beta[tid] - mu * gg;
  }
  __syncthreads();

  // ---- final fusion: 96 o x 8 float4 (32 d), coalesced out writes ----
  #pragma unroll
  for (int it = 0; it < 3; ++it) {
    int f = tid + it * 256;
    int op = f / 8, c4 = f & 7;
    float4 r;
    #pragma unroll
    for (int j = 0; j < 4; ++j) {
      int d = c4 * 4 + j;
      float v  = vsh[d * 100 + op];
      float ym = ysh[d * 100 + op];
      float gg = gsh[d];
      float y  = v * ssh[d] + osh[d];
      ((float*)&r)[j] = ym * gg + y * (1.0f - gg);
    }
    ((float4*)(out + (size_t)(b * OO + o0 + op) * DD))[c4] = r;
  }
}

// ---------------------------------------------------------------------------
extern "C" void kernel_launch(void* const* d_in, const int* in_sizes, int n_in,
                              void* d_out, int out_size, void* d_ws, size_t ws_size,
                              hipStream_t stream) {
  const float* x      = (const float*)d_in[0];
  const float* x_date = (const float*)d_in[1];
  const float* y_date = (const float*)d_in[2];
  const float* w1     = (const float*)d_in[3];
  const float* b1     = (const float*)d_in[4];
  const float* w2     = (const float*)d_in[5];
  const float* b2     = (const float*)d_in[6];
  const float* gamma  = (const float*)d_in[7];
  const float* beta   = (const float*)d_in[8];
  float* out = (float*)d_out;

  float* ws    = (float*)d_ws;
  float* V     = ws;                             // 196608  (B,D,O)
  float* ymean = ws + 196608;                    // 196608  (B,D,O)
  unsigned short* errb = (unsigned short*)(ws + 393216);   // 1024x512 bf16
  float* accum = ws + 655360;                    // 64      (sum, sumsq per d)
  float* xt    = ws + 655424;                    // 3145728 (B,192,L)
  float* xt2   = ws + 3801152;                   // 524288  (B,D,L)
  unsigned short* w1t = (unsigned short*)(ws + 4325440);   // 512x512 bf16 (m,l)

  prep_kernel<<<320, 256, 0, stream>>>(x, x_date, xt, xt2, w1, w1t, accum);
  fused_kernel<<<BB * DD, 256, 0, stream>>>(xt, xt2, y_date, V, ymean, errb, accum);
  tail_kernel<<<2 * BB, 256, 0, stream>>>(errb, w1t, b1, w2, b2, V, ymean,
                                          accum, gamma, beta, out);
}